// Round 18
// baseline (84.691 us; speedup 1.0000x reference)
//
#include <hip/hip_runtime.h>
#include <hip/hip_bf16.h>

typedef __bf16 bf16x8 __attribute__((ext_vector_type(8)));
typedef __bf16 bf16x4 __attribute__((ext_vector_type(4)));
typedef float  f32x4  __attribute__((ext_vector_type(4)));
typedef unsigned int u32x4 __attribute__((ext_vector_type(4)));

// ---------------------------------------------------------------------------
// Fused transpose+cast for both params in ONE launch (proven R5/R6).
//   blocks [0,512):   At[128][4096]  = bf16(A[4096][128])^T
//   blocks [512,1024): Bt[4096][128] = bf16(B[128][4096])^T
// ---------------------------------------------------------------------------
__global__ void tcast2(const float* __restrict__ A, __bf16* __restrict__ At,
                       const float* __restrict__ B, __bf16* __restrict__ Bt) {
    __shared__ float tile[32][33];
    int b = blockIdx.x;
    const float* src;
    __bf16* dst;
    int R, C, bxi, byi;
    if (b < 512) { src = A; dst = At; R = 4096; C = 128;  bxi = b & 3;   byi = b >> 2; }
    else { b -= 512; src = B; dst = Bt; R = 128;  C = 4096; bxi = b & 127; byi = b >> 7; }
    const int bc = bxi * 32;   // col base in src
    const int br = byi * 32;   // row base in src
    const int tx = threadIdx.x & 31;
    const int ty = threadIdx.x >> 5;  // 0..7
#pragma unroll
    for (int p = 0; p < 4; ++p)
        tile[ty + p * 8][tx] = src[(size_t)(br + ty + p * 8) * C + bc + tx];
    __syncthreads();
#pragma unroll
    for (int p = 0; p < 4; ++p)
        dst[(size_t)(bc + ty + p * 8) * R + br + tx] = (__bf16)tile[tx][ty + p * 8];
}

// ---------------------------------------------------------------------------
// FUSED2: row-local fusion.  Block b owns out rows [b*16, b*16+16).
//   out[r,:] = (inp[r,:] @ A) @ B  — U rows depend ONLY on inp rows, so the
//   whole pipeline is block-local; blocks drift independently and one
//   block's phase-B writes overlap other blocks' phase-A reads chip-wide.
// 512 blocks x 512 thr, 68 KB LDS -> 2 blocks/CU (the proven g1 config).
//
// Phase A (gemm1p structure, BM=16): U[16][128] in f32 regs; K-loop 64
//   tiles of BK=64, dbuf sI/sA, reg-staged fp32->bf16, single raw barrier
//   per tile with loads in flight across it.  8 waves = 1M x 8N.
// Transition: acc -> sU (bf16, swizzled), one barrier.
// Phase B (R6 gemm2 structure): hoist 4 U-fragments to regs; 32 col-tiles
//   j: double-buffered sB[128][128] (reg-staged, swizzled), swapped-operand
//   MFMA -> each thread stores one f32x4 of an out row (dwordx4).
// ---------------------------------------------------------------------------
__global__ __launch_bounds__(512, 4) void fused2(
        const float* __restrict__ inp,   // [8192][4096] f32
        const __bf16* __restrict__ At,   // [128][4096]
        const __bf16* __restrict__ Bt,   // [4096][128]
        float* __restrict__ out) {       // [8192][4096] f32
    __shared__ __align__(16) char smem[69632];
    auto sI = reinterpret_cast<__bf16 (*)[16][64]>(smem);           // [2][16][64]   4 KB
    auto sA = reinterpret_cast<__bf16 (*)[128][64]>(smem + 4096);   // [2][128][64] 32 KB
    auto sB = reinterpret_cast<__bf16 (*)[128][128]>(smem);         // [2][128][128] 64 KB (phase B)
    auto sU = reinterpret_cast<__bf16 (*)[128]>(smem + 65536);      // [16][128]     4 KB

    const int t    = threadIdx.x;
    const int lane = t & 63;
    const int wid  = t >> 6;          // 0..7
    const int brow = blockIdx.x * 16;
    const int fr   = lane & 15;
    const int g16  = lane >> 4;       // 0..3
    const int fk   = g16 << 3;        // 0,8,16,24
    const int wn   = wid << 4;        // 0..112

    // ---------------- Phase A: U[16][128] = inp_rows @ A ----------------
    const int irow = t >> 4;          // t<256: 0..15
    const int icol = (t & 15) << 2;   // 0..60
    f32x4 acc = {};
    f32x4 ireg;
    u32x4 areg[2];

    auto loadA = [&](int kt) {
        const int kg = kt * 64;
        if (t < 256)
            ireg = *reinterpret_cast<const f32x4*>(
                &inp[(size_t)(brow + irow) * 4096 + kg + icol]);
#pragma unroll
        for (int p = 0; p < 2; ++p) {
            const int c = t + p * 512;
            const int row = c >> 3, col = (c & 7) << 3;
            areg[p] = *reinterpret_cast<const u32x4*>(
                &At[(size_t)row * 4096 + kg + col]);
        }
    };
    auto storeA = [&](int buf) {
        if (t < 256) {
            bf16x4 h = { (__bf16)ireg[0], (__bf16)ireg[1],
                         (__bf16)ireg[2], (__bf16)ireg[3] };
            *reinterpret_cast<bf16x4*>(&sI[buf][irow][icol ^ ((irow & 7) << 3)]) = h;
        }
#pragma unroll
        for (int p = 0; p < 2; ++p) {
            const int c = t + p * 512;
            const int row = c >> 3, col = (c & 7) << 3;
            *reinterpret_cast<u32x4*>(&sA[buf][row][col ^ ((row & 7) << 3)]) = areg[p];
        }
    };
    auto computeA = [&](int buf) {
#pragma unroll
        for (int ks = 0; ks < 2; ++ks) {
            const int k = ks * 32 + fk;
            bf16x8 af = *reinterpret_cast<const bf16x8*>(
                &sI[buf][fr][k ^ ((fr & 7) << 3)]);
            const int nr = wn + fr;
            bf16x8 bfv = *reinterpret_cast<const bf16x8*>(
                &sA[buf][nr][k ^ ((nr & 7) << 3)]);
            acc = __builtin_amdgcn_mfma_f32_16x16x32_bf16(af, bfv, acc, 0, 0, 0);
        }
    };

    loadA(0);
    storeA(0);
    loadA(1);
    asm volatile("s_waitcnt lgkmcnt(0)" ::: "memory");
    __builtin_amdgcn_s_barrier();

    int cur = 0;
    for (int kt = 0; kt < 64; ++kt) {
        computeA(cur);
        if (kt + 1 < 64) storeA(cur ^ 1);
        if (kt + 2 < 64) loadA(kt + 2);
        asm volatile("s_waitcnt lgkmcnt(0)" ::: "memory");
        __builtin_amdgcn_s_barrier();
        cur ^= 1;
    }

    // ---------------- Transition: acc -> sU ----------------
    // C/D layout: col = lane&15 (N within wave slice), row = g16*4+v.
    {
        const int c = wn + fr;
#pragma unroll
        for (int v = 0; v < 4; ++v) {
            const int r = g16 * 4 + v;
            sU[r][c ^ ((r & 7) << 3)] = (__bf16)acc[v];
        }
    }
    asm volatile("s_waitcnt lgkmcnt(0)" ::: "memory");
    __builtin_amdgcn_s_barrier();     // sU visible; phase-A LDS reads done

    // ---------------- Phase B: out rows = U @ Bt^T ----------------
    bf16x8 uf[4];
#pragma unroll
    for (int ks = 0; ks < 4; ++ks)
        uf[ks] = *reinterpret_cast<const bf16x8*>(
            &sU[fr][(ks * 32 + fk) ^ ((fr & 7) << 3)]);

    u32x4 breg[4];
    auto loadB = [&](int j) {
#pragma unroll
        for (int p = 0; p < 4; ++p) {
            const int c = t + p * 512;
            const int row = c >> 4, col = (c & 15) << 3;
            breg[p] = *reinterpret_cast<const u32x4*>(
                &Bt[(size_t)(j * 128 + row) * 128 + col]);
        }
    };
    auto storeB = [&](int buf) {
#pragma unroll
        for (int p = 0; p < 4; ++p) {
            const int c = t + p * 512;
            const int row = c >> 4, col = (c & 15) << 3;
            *reinterpret_cast<u32x4*>(&sB[buf][row][col ^ ((row & 7) << 3)]) = breg[p];
        }
    };
    auto computeB = [&](int buf, int j) {
        f32x4 acc_s = {};
#pragma unroll
        for (int ks = 0; ks < 4; ++ks) {
            const int r = wn + fr;
            bf16x8 bfv = *reinterpret_cast<const bf16x8*>(
                &sB[buf][r][(ks * 32 + fk) ^ ((r & 7) << 3)]);
            acc_s = __builtin_amdgcn_mfma_f32_16x16x32_bf16(bfv, uf[ks], acc_s, 0, 0, 0);
        }
        // swapped C/D: out[row = brow+fr][cols = j*128 + wn + g16*4 .. +3]
        *reinterpret_cast<f32x4*>(
            &out[(size_t)(brow + fr) * 4096 + j * 128 + wn + (g16 << 2)]) = acc_s;
    };

    loadB(0);
    storeB(0);          // overwrites phase-A LDS area — reads done (barrier above)
    loadB(1);
    asm volatile("s_waitcnt lgkmcnt(0)" ::: "memory");
    __builtin_amdgcn_s_barrier();

    cur = 0;
    for (int j = 0; j < 32; ++j) {
        computeB(cur, j);
        if (j + 1 < 32) storeB(cur ^ 1);
        if (j + 2 < 32) loadB(j + 2);
        asm volatile("s_waitcnt lgkmcnt(0)" ::: "memory");
        __builtin_amdgcn_s_barrier();
        cur ^= 1;
    }
}

// ---------------------------------------------------------------------------
extern "C" void kernel_launch(void* const* d_in, const int* in_sizes, int n_in,
                              void* d_out, int out_size, void* d_ws, size_t ws_size,
                              hipStream_t stream) {
    const float* inp = (const float*)d_in[0];   // [8192,4096]
    const float* A   = (const float*)d_in[1];   // [4096,128]
    const float* B   = (const float*)d_in[2];   // [128,4096]
    float* out = (float*)d_out;                 // [8192,4096]

    char* ws = (char*)d_ws;
    __bf16* At = (__bf16*)(ws);                 // [128][4096]  1 MB
    __bf16* Bt = (__bf16*)(ws + (1 << 20));     // [4096][128]  1 MB

    tcast2<<<1024, 256, 0, stream>>>(A, At, B, Bt);
    fused2<<<512, 512, 0, stream>>>(inp, At, Bt, out);
}

// Round 19
// 73.817 us; speedup vs baseline: 1.1473x; 1.1473x over previous
//
#include <hip/hip_runtime.h>
#include <hip/hip_bf16.h>

typedef __bf16 bf16x8 __attribute__((ext_vector_type(8)));
typedef __bf16 bf16x4 __attribute__((ext_vector_type(4)));
typedef float  f32x4  __attribute__((ext_vector_type(4)));
typedef unsigned int u32x4 __attribute__((ext_vector_type(4)));

// ---------------------------------------------------------------------------
// Fused transpose+cast for both params in ONE launch.
//   blocks [0,512):   At[128][4096]  = bf16(A[4096][128])^T
//   blocks [512,1024): Bt[4096][128] = bf16(B[128][4096])^T
// ---------------------------------------------------------------------------
__global__ void tcast2(const float* __restrict__ A, __bf16* __restrict__ At,
                       const float* __restrict__ B, __bf16* __restrict__ Bt) {
    __shared__ float tile[32][33];
    int b = blockIdx.x;
    const float* src;
    __bf16* dst;
    int R, C, bxi, byi;
    if (b < 512) { src = A; dst = At; R = 4096; C = 128;  bxi = b & 3;   byi = b >> 2; }
    else { b -= 512; src = B; dst = Bt; R = 128;  C = 4096; bxi = b & 127; byi = b >> 7; }
    const int bc = bxi * 32;   // col base in src
    const int br = byi * 32;   // row base in src
    const int tx = threadIdx.x & 31;
    const int ty = threadIdx.x >> 5;  // 0..7
#pragma unroll
    for (int p = 0; p < 4; ++p)
        tile[ty + p * 8][tx] = src[(size_t)(br + ty + p * 8) * C + bc + tx];
    __syncthreads();
#pragma unroll
    for (int p = 0; p < 4; ++p)
        dst[(size_t)(bc + ty + p * 8) * R + br + tx] = (__bf16)tile[tx][ty + p * 8];
}

// ---------------------------------------------------------------------------
// GEMM1 (K-split, proven R4): Up[ky][8192][128](bf16) = inp @ A-slice.
// grid (256, KSPLIT) x 512 threads (8 waves: 2M x 4N). BM=32, BK=64.
// Double-buffered LDS, reg-staged fp32->bf16 convert.  KSPLIT=2 -> 2
// blocks/CU: barrier drains overlap across blocks.
// Measured 26.6 us (R7) = 76% of pure-read HBM BW for its 128 MB inp read;
// insensitive to 8 structural variants (R5/R8/R9/R12/R13/R16).
// ---------------------------------------------------------------------------
__global__ __launch_bounds__(512, 1) void gemm1b(const float* __restrict__ inp,
                                                 const __bf16* __restrict__ At,
                                                 __bf16* __restrict__ Uout,
                                                 int ktiles) {
    __shared__ __align__(16) __bf16 sI[2][32][64];    // 2 x 4 KB
    __shared__ __align__(16) __bf16 sA[2][128][64];   // 2 x 16 KB
    const int t     = threadIdx.x;
    const int brow  = blockIdx.x * 32;
    const int ktoff = blockIdx.y * ktiles;
    __bf16* Up = Uout + (size_t)blockIdx.y * 8192 * 128;
    const int lane = t & 63;
    const int wid  = t >> 6;
    const int wm   = (wid >> 2) << 4;   // 0 / 16
    const int wn   = (wid & 3) << 5;    // 0 / 32 / 64 / 96

    const int irow = t >> 4;            // 0..31
    const int icol = (t & 15) << 2;     // 0..60, step 4
    const int fr = lane & 15;
    const int fk = (lane >> 4) << 3;    // 0,8,16,24

    f32x4 acc[2] = {};
    f32x4 ireg;
    u32x4 areg[2];

    auto load_tile = [&](int kt) {
        const int kg = (ktoff + kt) * 64;
        ireg = *reinterpret_cast<const f32x4*>(
            &inp[(size_t)(brow + irow) * 4096 + kg + icol]);
#pragma unroll
        for (int p = 0; p < 2; ++p) {
            const int c = t + p * 512;
            const int row = c >> 3, col = (c & 7) << 3;
            areg[p] = *reinterpret_cast<const u32x4*>(
                &At[(size_t)row * 4096 + kg + col]);
        }
    };
    auto store_tile = [&](int buf) {
        bf16x4 h = { (__bf16)ireg[0], (__bf16)ireg[1], (__bf16)ireg[2], (__bf16)ireg[3] };
        *reinterpret_cast<bf16x4*>(&sI[buf][irow][icol ^ ((irow & 7) << 3)]) = h;
#pragma unroll
        for (int p = 0; p < 2; ++p) {
            const int c = t + p * 512;
            const int row = c >> 3, col = (c & 7) << 3;
            *reinterpret_cast<u32x4*>(&sA[buf][row][col ^ ((row & 7) << 3)]) = areg[p];
        }
    };

    load_tile(0);
    store_tile(0);
    int cur = 0;
    for (int kt = 0; kt < ktiles; ++kt) {
        if (kt < ktiles - 1) load_tile(kt + 1);   // overlap with compute below
        __syncthreads();                          // buf[cur] writes visible
#pragma unroll
        for (int ks = 0; ks < 2; ++ks) {
            const int k = ks * 32 + fk;
            const int ar = wm + fr;
            bf16x8 af = *reinterpret_cast<const bf16x8*>(
                &sI[cur][ar][k ^ ((ar & 7) << 3)]);
#pragma unroll
            for (int n = 0; n < 2; ++n) {
                const int nr = wn + n * 16 + fr;
                bf16x8 bfv = *reinterpret_cast<const bf16x8*>(
                    &sA[cur][nr][k ^ ((nr & 7) << 3)]);
                acc[n] = __builtin_amdgcn_mfma_f32_16x16x32_bf16(af, bfv, acc[n], 0, 0, 0);
            }
        }
        __syncthreads();                          // all reads of buf[cur] done
        if (kt < ktiles - 1) store_tile(cur ^ 1);
        cur ^= 1;
    }

    // epilogue: Up is bf16 [8192][128].  C/D: col=lane&15, row=(lane>>4)*4+v
    const int orow = brow + wm + ((lane >> 4) << 2);
#pragma unroll
    for (int n = 0; n < 2; ++n)
#pragma unroll
        for (int v = 0; v < 4; ++v)
            Up[(size_t)(orow + v) * 128 + wn + n * 16 + fr] = (__bf16)acc[n][v];
}

// ---------------------------------------------------------------------------
// Reduce ksplit partials: U = bf16(sum_j Up[j]).  1M elems.
// Separate pass is CHEAPER than merging into gemm2: merge re-reads each
// stripe 32x through L2 (128 MB) vs this single 6 MB pass (R11/R13 evidence).
// ---------------------------------------------------------------------------
__global__ void reduceU(const __bf16* __restrict__ Up, __bf16* __restrict__ U,
                        int ksplit) {
    const size_t i = ((size_t)blockIdx.x * 256 + threadIdx.x) * 8;
    float s[8] = {};
    for (int j = 0; j < ksplit; ++j) {
        bf16x8 a = *reinterpret_cast<const bf16x8*>(Up + (size_t)j * 8192 * 128 + i);
#pragma unroll
        for (int e = 0; e < 8; ++e) s[e] += (float)a[e];
    }
    bf16x8 r;
#pragma unroll
    for (int e = 0; e < 8; ++e) r[e] = (__bf16)s[e];
    *reinterpret_cast<bf16x8*>(U + i) = r;
}

// ---------------------------------------------------------------------------
// GEMM2 (proven R6): out[8192][4096](f32) = U[8192][128](bf16) @ Bt^T.
// K=128 fully staged. BM=64 x BN=128. 4096 blocks x 256 thr (4 waves 2x2).
// Operand-swapped MFMA -> transposed C/D -> each thread holds 4 consecutive
// out columns -> dwordx4 stores.  Bijective XCD chunk swizzle (4096 = 8x512).
// LDS-staged Bt is load-bearing: direct-global Bt fragments cost +10 us (R17).
// ---------------------------------------------------------------------------
__global__ __launch_bounds__(256, 1) void gemm2(const __bf16* __restrict__ U,
                                                const __bf16* __restrict__ Bt,
                                                float* __restrict__ out) {
    __shared__ __align__(16) __bf16 sU[64][128];    // 16 KB
    __shared__ __align__(16) __bf16 sB[128][128];   // 32 KB
    const int t    = threadIdx.x;
    const int lane = t & 63;
    const int wid  = t >> 6;
    const int bx0  = blockIdx.x;
    const int bx   = (bx0 & 7) * 512 + (bx0 >> 3);  // XCD-contiguous chunks
    const int brow = (bx >> 5) * 64;    // 128 row tiles
    const int bcol = (bx & 31) * 128;   // 32 col tiles

    // stage U tile (64 rows x 128 k)
#pragma unroll
    for (int p = 0; p < 4; ++p) {
        const int c = t + p * 256;
        const int row = c >> 4, col = (c & 15) << 3;
        u32x4 v = *reinterpret_cast<const u32x4*>(&U[(size_t)(brow + row) * 128 + col]);
        *reinterpret_cast<u32x4*>(&sU[row][col ^ ((row & 7) << 3)]) = v;
    }
    // stage Bt tile (128 n-rows x 128 k)
#pragma unroll
    for (int p = 0; p < 8; ++p) {
        const int c = t + p * 256;
        const int row = c >> 4, col = (c & 15) << 3;
        u32x4 v = *reinterpret_cast<const u32x4*>(&Bt[(size_t)(bcol + row) * 128 + col]);
        *reinterpret_cast<u32x4*>(&sB[row][col ^ ((row & 7) << 3)]) = v;
    }
    __syncthreads();

    const int wm = (wid >> 1) << 5;   // 0 / 32
    const int wn = (wid & 1) << 6;    // 0 / 64
    const int fr = lane & 15;
    const int fk = (lane >> 4) << 3;

    // acc_s[nf][mf]: swapped-operand accumulators (transposed C/D)
    f32x4 acc_s[4][2] = {};
#pragma unroll
    for (int ks = 0; ks < 4; ++ks) {
        const int k = ks * 32 + fk;
        bf16x8 af[2];
#pragma unroll
        for (int am = 0; am < 2; ++am) {
            const int r = wm + am * 16 + fr;
            af[am] = *reinterpret_cast<const bf16x8*>(&sU[r][k ^ ((r & 7) << 3)]);
        }
#pragma unroll
        for (int bn = 0; bn < 4; ++bn) {
            const int r = wn + bn * 16 + fr;
            bf16x8 bfv = *reinterpret_cast<const bf16x8*>(&sB[r][k ^ ((r & 7) << 3)]);
#pragma unroll
            for (int am = 0; am < 2; ++am)
                acc_s[bn][am] = __builtin_amdgcn_mfma_f32_16x16x32_bf16(
                    bfv, af[am], acc_s[bn][am], 0, 0, 0);
        }
    }

    // epilogue (swapped layout): f32x4 per (bn,am) -> dwordx4 stores
    const int g4 = (lane >> 4) << 2;
#pragma unroll
    for (int am = 0; am < 2; ++am) {
        const int orow = brow + wm + am * 16 + fr;
#pragma unroll
        for (int bn = 0; bn < 4; ++bn) {
            const int ocol = bcol + wn + bn * 16 + g4;
            *reinterpret_cast<f32x4*>(&out[(size_t)orow * 4096 + ocol]) = acc_s[bn][am];
        }
    }
}

// ---------------------------------------------------------------------------
extern "C" void kernel_launch(void* const* d_in, const int* in_sizes, int n_in,
                              void* d_out, int out_size, void* d_ws, size_t ws_size,
                              hipStream_t stream) {
    const float* inp = (const float*)d_in[0];   // [8192,4096]
    const float* A   = (const float*)d_in[1];   // [4096,128]
    const float* B   = (const float*)d_in[2];   // [128,4096]
    float* out = (float*)d_out;                 // [8192,4096]

    char* ws = (char*)d_ws;
    __bf16* At = (__bf16*)(ws);                       // [128][4096]        1 MB
    __bf16* Bt = (__bf16*)(ws + (1 << 20));           // [4096][128]        1 MB
    __bf16* U  = (__bf16*)(ws + (2 << 20));           // [8192][128]        2 MB
    __bf16* Up = (__bf16*)(ws + (4 << 20));           // [2][8192][128]     4 MB

    tcast2<<<1024, 256, 0, stream>>>(A, At, B, Bt);

    if (ws_size >= (size_t)(8 << 20)) {
        gemm1b<<<dim3(256, 2), 512, 0, stream>>>(inp, At, Up, 32);
        reduceU<<<512, 256, 0, stream>>>(Up, U, 2);
    } else {
        gemm1b<<<dim3(256, 1), 512, 0, stream>>>(inp, At, U, 64);
    }

    gemm2<<<4096, 256, 0, stream>>>(U, Bt, out);
}